// Round 2
// 566.917 us; speedup vs baseline: 1.8307x; 1.8307x over previous
//
#include <hip/hip_runtime.h>

typedef long long i64;

// ---------------------------------------------------------------------------
// S1=S2=256, B=8, C0=32.  d_out = 22,151,168 float32 = REAL parts of:
//   out0 (8,32,256,129) | out1 (alias of out0) | out2 (8,64,128,64) | out3 (8,64,64,32)
// R8: wave-per-point branch1/branch2 (intermediates in LDS, no spills).
// vs R7 attempt: wd2/wu2 NOT staged in LDS (read coalesced from global,
// L2-resident) so branch2 static LDS stays under 64 KB -> 2 blocks/CU and
// no oversized-LDS launch risk.
// ---------------------------------------------------------------------------
#define BB   8
#define SS1  256
#define MM2  129
#define SP0  (SS1*MM2)    // 33024

#define O0 0LL
#define O1 8454144LL
#define O2 16908288LL
#define O3 21102592LL
// total floats = 22151168

__device__ __forceinline__ float ldf(const float* p, i64 i, i64 cap) {
    return (i >= 0 && i < cap) ? p[i] : 0.0f;
}
__device__ __forceinline__ void stf(float* p, i64 i, i64 cap, float v) {
    if (i >= 0 && i < cap) p[i] = v;
}

__device__ __forceinline__ float tanh_fast(float x) {
    float a = fabsf(x);
    float t = __expf(-2.0f * a);
    float r = (1.0f - t) / (1.0f + t);
    return copysignf(r, x);
}
__device__ __forceinline__ float gelu_f(float x) {
    // jax.nn.gelu(approximate=True)
    float inner = 0.7978845608028654f * (x + 0.044715f * x * x * x);
    return 0.5f * x * (1.0f + tanh_fast(inner));
}

// features for point (b, x, y): fr/fi[6] = k-powers, rp[3] = Re-powers
__device__ __forceinline__ void compute_features(
    int b, int x, int y, const float* __restrict__ Re,
    float* fr, float* fi, float* rp)
{
    float kv0 = (x < 128) ? (float)x : (float)(x - 256);
    float kv1 = (y < 128) ? (float)y : -128.0f;
    const float P[3] = {1.0f/3.0f, 2.0f/3.0f, 1.0f};
    #pragma unroll
    for (int d = 0; d < 2; d++) {
        float k = d ? kv1 : kv0;
        float lg = __logf(fabsf(k));
        #pragma unroll
        for (int f = 0; f < 3; f++) {
            int c = f * 2 + d;
            float m = __expf(P[f] * lg);
            if (k == 0.0f)      { fr[c] = 0.0f; fi[c] = 0.0f; }
            else if (k > 0.0f)  { fr[c] = m;    fi[c] = 0.0f; }
            else {
                float ang = P[f] * 3.14159274101257f;
                fr[c] = m * __cosf(ang);
                fi[c] = m * __sinf(ang);
            }
        }
    }
    float lre = __logf(Re[b]);
    #pragma unroll
    for (int f = 0; f < 3; f++) rp[f] = __expf(P[f] * lre);
}

// ---------------------------------------------------------------------------
// K1 (unchanged): thread-per-point, real(x1_0) -> out0, out1
// ---------------------------------------------------------------------------
__device__ __forceinline__ void l0_masked_v(
    int b, int x, int y,
    const float* __restrict__ xr, const float* __restrict__ xi,
    const float* __restrict__ Re,
    const float2* s_w1, const float2* s_b1,
    const float2* s_w2, const float2* s_b2,
    float* vr, float* vi)
{
    float fr[6], fi[6], rp[3];
    compute_features(b, x, y, Re, fr, fi, rp);

    float hr[32], hi[32];
    #pragma unroll
    for (int o = 0; o < 32; o++) {
        float ar = s_b1[o].x, ai = s_b1[o].y;
        #pragma unroll
        for (int i = 0; i < 6; i++) {
            float2 w = s_w1[o * 9 + i];
            ar += w.x * fr[i] - w.y * fi[i];
            ai += w.x * fi[i] + w.y * fr[i];
        }
        #pragma unroll
        for (int i = 0; i < 3; i++) {
            float2 w = s_w1[o * 9 + 6 + i];
            ar += w.x * rp[i];
            ai += w.y * rp[i];
        }
        hr[o] = gelu_f(ar);
        hi[o] = gelu_f(ai);
    }

    i64 base0 = (i64)b * 32 * SP0 + (i64)x * MM2 + y;
    for (int c = 0; c < 32; c++) {
        float rr = s_b2[c].x, ri = s_b2[c].y;
        #pragma unroll
        for (int i = 0; i < 32; i++) {
            float2 w = s_w2[c * 32 + i];
            rr += w.x * hr[i] - w.y * hi[i];
            ri += w.x * hi[i] + w.y * hr[i];
        }
        float xre = xr[base0 + (i64)c * SP0];
        float xim = xi[base0 + (i64)c * SP0];
        float pr = xre * rr - xim * ri;
        float pi = xre * ri + xim * rr;
        if (sqrtf(pr * pr + pi * pi) <= 0.05f) { pr = 0.0f; pi = 0.0f; }
        vr[c] = pr + 1.0f;
        vi[c] = pi;
    }
}

#define STAGE_L0()                                                            \
    for (int t = threadIdx.x; t < 1024; t += 256) {                           \
        s_w2[t] = make_float2(w2r[t], w2i[t]);                                \
        s_w0[t] = make_float2(w0r[t], w0i[t]);                                \
        if (t < 288) s_w1[t] = make_float2(w1r[t], w1i[t]);                   \
        if (t < 32) {                                                         \
            s_b1[t] = make_float2(b1r[t], b1i[t]);                            \
            s_b2[t] = make_float2(b2r[t], b2i[t]);                            \
        }                                                                     \
    }

__global__ __launch_bounds__(256) void k_level0(
    const float* __restrict__ xr, const float* __restrict__ xi,
    const float* __restrict__ Re,
    const float* __restrict__ w1r, const float* __restrict__ w1i,
    const float* __restrict__ b1r, const float* __restrict__ b1i,
    const float* __restrict__ w2r, const float* __restrict__ w2i,
    const float* __restrict__ b2r, const float* __restrict__ b2i,
    const float* __restrict__ w0r, const float* __restrict__ w0i,
    float* __restrict__ of, i64 capf)
{
    __shared__ float2 s_w1[288], s_b1[32], s_w2[1024], s_b2[32], s_w0[1024];
    STAGE_L0();
    __syncthreads();

    int idx = blockIdx.x * 256 + threadIdx.x;
    if (idx >= BB * SP0) return;
    int y  = idx % MM2;
    int t2 = idx / MM2;
    int x  = t2 % SS1;
    int b  = t2 / SS1;

    float vr[32], vi[32];
    l0_masked_v(b, x, y, xr, xi, Re, s_w1, s_b1, s_w2, s_b2, vr, vi);

    i64 base0 = (i64)b * 32 * SP0 + (i64)x * MM2 + y;
    #pragma unroll
    for (int o = 0; o < 32; o++) {
        float a = 0.0f;
        #pragma unroll
        for (int c = 0; c < 32; c++) {
            float2 w = s_w0[c * 32 + o];   // w0[i][o] ('io' einsum)
            a += w.x * vr[c] - w.y * vi[c];
        }
        float g = gelu_f(a);
        i64 oi = base0 + (i64)o * SP0;
        stf(of, O0 + oi, capf, g);
        stf(of, O1 + oi, capf, g);
    }
}

// ---------------------------------------------------------------------------
// Wave-per-point kernels.  Block = 512 threads = 8 waves = 8 points.
// Per-point LDS scratch (float2): H[32] | V[32] | X1[32] | V1[64] | (V2[64])
// ---------------------------------------------------------------------------
#define PH  0
#define PV  32
#define PX1 64
#define PV1 96
#define PV2 160

// ---------------------------------------------------------------------------
// K2: corner1 \ corner2 points.  idx in [0,65536): y=idx&63, r1=(idx>>6)&127,
// b=idx>>13.  Block covers 8 consecutive y at fixed (b,r1).
// LDS: 48K weights + 10K scratch + 1K = ~60 KB -> 2 blocks/CU.
// ---------------------------------------------------------------------------
__global__ __launch_bounds__(512, 4) void k_branch1(
    const float* __restrict__ xr, const float* __restrict__ xi,
    const float* __restrict__ Re,
    const float* __restrict__ w1r, const float* __restrict__ w1i,
    const float* __restrict__ b1r, const float* __restrict__ b1i,
    const float* __restrict__ w2r, const float* __restrict__ w2i,
    const float* __restrict__ b2r, const float* __restrict__ b2i,
    const float* __restrict__ w0r, const float* __restrict__ w0i,
    const float* __restrict__ wd1r, const float* __restrict__ wd1i,
    const float* __restrict__ wu1r, const float* __restrict__ wu1i,
    float* __restrict__ of, i64 capf)
{
    int base = blockIdx.x * 8;
    int y0 = base & 63;
    int r1 = (base >> 6) & 127;
    int b  = base >> 13;
    // corner2 points handled by k_branch2 (uniform over block: 8|32)
    if ((y0 < 32) && (r1 < 32 || r1 >= 96)) return;
    int x0 = (r1 < 64) ? r1 : r1 + 128;

    __shared__ float2 s_w2t[1024];           // [i*32+c] (transposed 'oi')
    __shared__ float2 s_w0[1024];            // [i*32+o] natural 'io'
    __shared__ float2 s_wd1[2048];           // [i*64+o] natural 'io'
    __shared__ float2 s_wu1[2048];           // [c*32+o] natural 'io'
    __shared__ float2 s_pt[8][160];
    __shared__ float  s_u[8][32];

    for (int t = threadIdx.x; t < 1024; t += 512) {
        int c = t >> 5, i = t & 31;
        s_w2t[i * 32 + c] = make_float2(w2r[t], w2i[t]);
        s_w0[t] = make_float2(w0r[t], w0i[t]);
    }
    for (int t = threadIdx.x; t < 2048; t += 512) {
        s_wd1[t] = make_float2(wd1r[t], wd1i[t]);
        s_wu1[t] = make_float2(wu1r[t], wu1i[t]);
    }

    int p = threadIdx.x >> 6;         // wave = point
    int lane = threadIdx.x & 63;
    int y = y0 + p;

    // phase A: features + layer1 (9 -> 32), lanes 0..31; w1/b1 from global
    if (lane < 32) {
        float fr[6], fi[6], rp[3];
        compute_features(b, x0, y, Re, fr, fi, rp);
        int o = lane;
        float ar = b1r[o], ai = b1i[o];
        #pragma unroll
        for (int i = 0; i < 6; i++) {
            float wr = w1r[o * 9 + i], wi = w1i[o * 9 + i];
            ar += wr * fr[i] - wi * fi[i];
            ai += wr * fi[i] + wi * fr[i];
        }
        #pragma unroll
        for (int f = 0; f < 3; f++) {
            ar += w1r[o * 9 + 6 + f] * rp[f];
            ai += w1i[o * 9 + 6 + f] * rp[f];
        }
        s_pt[p][PH + o] = make_float2(gelu_f(ar), gelu_f(ai));
    }
    __syncthreads();

    // phase B: layer2 (32 -> 32) + x*rf + mask + skip(+1 real)
    if (lane < 32) {
        int c = lane;
        float rr = b2r[c], ri = b2i[c];
        #pragma unroll
        for (int i = 0; i < 32; i++) {
            float2 w = s_w2t[i * 32 + c];
            float2 h = s_pt[p][PH + i];
            rr += w.x * h.x - w.y * h.y;
            ri += w.x * h.y + w.y * h.x;
        }
        i64 xoff = ((i64)b * 32 + c) * SP0 + (i64)x0 * MM2 + y;
        float xre = xr[xoff], xim = xi[xoff];
        float pr = xre * rr - xim * ri;
        float pi = xre * ri + xim * rr;
        if (sqrtf(pr * pr + pi * pi) <= 0.05f) { pr = 0.0f; pi = 0.0f; }
        s_pt[p][PV + c] = make_float2(pr + 1.0f, pi);
    }
    __syncthreads();

    // phase C: W0 mix -> x1 (complex); lane halves split real/imag parts
    {
        int o = lane & 31, part = lane >> 5;
        const float* vv = (const float*)&s_pt[p][PV];
        int ia = part ? 1 : 0, ib = part ? 0 : 1;
        float sgn = part ? 1.0f : -1.0f;
        float a = 0.0f;
        #pragma unroll
        for (int c2 = 0; c2 < 32; c2++) {
            float2 w = s_w0[c2 * 32 + o];
            a += w.x * vv[2 * c2 + ia] + sgn * w.y * vv[2 * c2 + ib];
        }
        a = gelu_f(a);
        ((float*)&s_pt[p][PX1 + o])[part] = a;
    }
    __syncthreads();

    // phase D: Wd1 (32 -> 64) -> v1 = cgelu + (1 real)
    {
        float ar = 0.0f, ai = 0.0f;
        #pragma unroll
        for (int i2 = 0; i2 < 32; i2++) {
            float2 w = s_wd1[i2 * 64 + lane];
            float2 x1 = s_pt[p][PX1 + i2];
            ar += w.x * x1.x - w.y * x1.y;
            ai += w.x * x1.y + w.y * x1.x;
        }
        s_pt[p][PV1 + lane] = make_float2(gelu_f(ar) + 1.0f, gelu_f(ai));
    }
    __syncthreads();

    // out2 store (y-contiguous): t -> (o, ty)
    {
        int o = threadIdx.x >> 3, ty = threadIdx.x & 7;
        float v = s_pt[ty][PV1 + o].x;
        stf(of, O2 + ((i64)((i64)b * 64 + o) * 128 + r1) * 64 + (y0 + ty), capf, v);
    }

    // phase E: Wu1 real part (64 -> 32); lane halves split c-range, shfl-combine
    {
        int o = lane & 31, half = lane >> 5;
        float acc = 0.0f;
        #pragma unroll
        for (int c2 = 0; c2 < 32; c2++) {
            int c = half * 32 + c2;
            float2 w = s_wu1[c * 32 + o];
            float2 v1 = s_pt[p][PV1 + c];
            acc += w.x * v1.x - w.y * v1.y;
        }
        acc += __shfl_xor(acc, 32);
        if (lane < 32) s_u[p][o] = gelu_f(acc);
    }
    __syncthreads();

    // out0/out1 RMW (y-contiguous)
    if (threadIdx.x < 256) {
        int o = threadIdx.x >> 3, ty = threadIdx.x & 7;
        i64 oi = ((i64)b * 32 + o) * SP0 + (i64)x0 * MM2 + (y0 + ty);
        float cur = ldf(of, O0 + oi, capf) + s_u[ty][o];
        stf(of, O0 + oi, capf, cur);
        stf(of, O1 + oi, capf, cur);
    }
}

// ---------------------------------------------------------------------------
// K3: corner2 points.  idx in [0,16384): y=idx&31, r2=(idx>>5)&63, b=idx>>11.
// wd2/wu2 read straight from global (coalesced 256B/wave, L2-resident) so
// static LDS stays < 64 KB -> 2 blocks/CU.
// ---------------------------------------------------------------------------
__global__ __launch_bounds__(512, 4) void k_branch2(
    const float* __restrict__ xr, const float* __restrict__ xi,
    const float* __restrict__ Re,
    const float* __restrict__ w1r, const float* __restrict__ w1i,
    const float* __restrict__ b1r, const float* __restrict__ b1i,
    const float* __restrict__ w2r, const float* __restrict__ w2i,
    const float* __restrict__ b2r, const float* __restrict__ b2i,
    const float* __restrict__ w0r, const float* __restrict__ w0i,
    const float* __restrict__ wd1r, const float* __restrict__ wd1i,
    const float* __restrict__ wu1r, const float* __restrict__ wu1i,
    const float* __restrict__ wd2r, const float* __restrict__ wd2i,
    const float* __restrict__ wu2r, const float* __restrict__ wu2i,
    float* __restrict__ of, i64 capf)
{
    int base = blockIdx.x * 8;
    int y0 = base & 31;
    int r2 = (base >> 5) & 63;
    int b  = base >> 11;
    int r1 = (r2 < 32) ? r2 : r2 + 64;
    int x0 = (r1 < 64) ? r1 : r1 + 128;

    __shared__ float2 s_w2t[1024];
    __shared__ float2 s_w0[1024];
    __shared__ float2 s_wd1[2048];
    __shared__ float2 s_wu1[2048];
    __shared__ float2 s_pt[8][224];
    __shared__ float  s_u[8][32];

    for (int t = threadIdx.x; t < 1024; t += 512) {
        int c = t >> 5, i = t & 31;
        s_w2t[i * 32 + c] = make_float2(w2r[t], w2i[t]);
        s_w0[t] = make_float2(w0r[t], w0i[t]);
    }
    for (int t = threadIdx.x; t < 2048; t += 512) {
        s_wd1[t] = make_float2(wd1r[t], wd1i[t]);
        s_wu1[t] = make_float2(wu1r[t], wu1i[t]);
    }

    int p = threadIdx.x >> 6;
    int lane = threadIdx.x & 63;
    int y = y0 + p;

    // phase A
    if (lane < 32) {
        float fr[6], fi[6], rp[3];
        compute_features(b, x0, y, Re, fr, fi, rp);
        int o = lane;
        float ar = b1r[o], ai = b1i[o];
        #pragma unroll
        for (int i = 0; i < 6; i++) {
            float wr = w1r[o * 9 + i], wi = w1i[o * 9 + i];
            ar += wr * fr[i] - wi * fi[i];
            ai += wr * fi[i] + wi * fr[i];
        }
        #pragma unroll
        for (int f = 0; f < 3; f++) {
            ar += w1r[o * 9 + 6 + f] * rp[f];
            ai += w1i[o * 9 + 6 + f] * rp[f];
        }
        s_pt[p][PH + o] = make_float2(gelu_f(ar), gelu_f(ai));
    }
    __syncthreads();

    // phase B
    if (lane < 32) {
        int c = lane;
        float rr = b2r[c], ri = b2i[c];
        #pragma unroll
        for (int i = 0; i < 32; i++) {
            float2 w = s_w2t[i * 32 + c];
            float2 h = s_pt[p][PH + i];
            rr += w.x * h.x - w.y * h.y;
            ri += w.x * h.y + w.y * h.x;
        }
        i64 xoff = ((i64)b * 32 + c) * SP0 + (i64)x0 * MM2 + y;
        float xre = xr[xoff], xim = xi[xoff];
        float pr = xre * rr - xim * ri;
        float pi = xre * ri + xim * rr;
        if (sqrtf(pr * pr + pi * pi) <= 0.05f) { pr = 0.0f; pi = 0.0f; }
        s_pt[p][PV + c] = make_float2(pr + 1.0f, pi);
    }
    __syncthreads();

    // phase C
    {
        int o = lane & 31, part = lane >> 5;
        const float* vv = (const float*)&s_pt[p][PV];
        int ia = part ? 1 : 0, ib = part ? 0 : 1;
        float sgn = part ? 1.0f : -1.0f;
        float a = 0.0f;
        #pragma unroll
        for (int c2 = 0; c2 < 32; c2++) {
            float2 w = s_w0[c2 * 32 + o];
            a += w.x * vv[2 * c2 + ia] + sgn * w.y * vv[2 * c2 + ib];
        }
        a = gelu_f(a);
        ((float*)&s_pt[p][PX1 + o])[part] = a;
    }
    __syncthreads();

    // phase D: Wd1 -> v1
    {
        float ar = 0.0f, ai = 0.0f;
        #pragma unroll
        for (int i2 = 0; i2 < 32; i2++) {
            float2 w = s_wd1[i2 * 64 + lane];
            float2 x1 = s_pt[p][PX1 + i2];
            ar += w.x * x1.x - w.y * x1.y;
            ai += w.x * x1.y + w.y * x1.x;
        }
        s_pt[p][PV1 + lane] = make_float2(gelu_f(ar) + 1.0f, gelu_f(ai));
    }
    __syncthreads();

    // phase D2: Wd2 (64 -> 64) -> v2 ; weights from global (coalesced)
    {
        float ar = 0.0f, ai = 0.0f;
        #pragma unroll 8
        for (int c2 = 0; c2 < 64; c2++) {
            float wr = wd2r[c2 * 64 + lane], wi = wd2i[c2 * 64 + lane];
            float2 v1 = s_pt[p][PV1 + c2];
            ar += wr * v1.x - wi * v1.y;
            ai += wr * v1.y + wi * v1.x;
        }
        s_pt[p][PV2 + lane] = make_float2(gelu_f(ar) + 1.0f, gelu_f(ai));
    }
    __syncthreads();

    // out3 store (y-contiguous)
    {
        int o = threadIdx.x >> 3, ty = threadIdx.x & 7;
        float v = s_pt[ty][PV2 + o].x;
        stf(of, O3 + ((i64)((i64)b * 64 + o) * 64 + r2) * 32 + (y0 + ty), capf, v);
    }

    // phase U2: v1 += cgelu(Wu2 mix of v2) ; weights from global (coalesced)
    {
        float ar = 0.0f, ai = 0.0f;
        #pragma unroll 8
        for (int c2 = 0; c2 < 64; c2++) {
            float wr = wu2r[c2 * 64 + lane], wi = wu2i[c2 * 64 + lane];
            float2 v2 = s_pt[p][PV2 + c2];
            ar += wr * v2.x - wi * v2.y;
            ai += wr * v2.y + wi * v2.x;
        }
        float2 v1 = s_pt[p][PV1 + lane];
        v1.x += gelu_f(ar);
        v1.y += gelu_f(ai);
        s_pt[p][PV1 + lane] = v1;
    }
    __syncthreads();

    // out2 store (y-contiguous)
    {
        int o = threadIdx.x >> 3, ty = threadIdx.x & 7;
        float v = s_pt[ty][PV1 + o].x;
        stf(of, O2 + ((i64)((i64)b * 64 + o) * 128 + r1) * 64 + (y0 + ty), capf, v);
    }

    // phase E: Wu1 real part on updated v1
    {
        int o = lane & 31, half = lane >> 5;
        float acc = 0.0f;
        #pragma unroll
        for (int c2 = 0; c2 < 32; c2++) {
            int c = half * 32 + c2;
            float2 w = s_wu1[c * 32 + o];
            float2 v1 = s_pt[p][PV1 + c];
            acc += w.x * v1.x - w.y * v1.y;
        }
        acc += __shfl_xor(acc, 32);
        if (lane < 32) s_u[p][o] = gelu_f(acc);
    }
    __syncthreads();

    if (threadIdx.x < 256) {
        int o = threadIdx.x >> 3, ty = threadIdx.x & 7;
        i64 oi = ((i64)b * 32 + o) * SP0 + (i64)x0 * MM2 + (y0 + ty);
        float cur = ldf(of, O0 + oi, capf) + s_u[ty][o];
        stf(of, O0 + oi, capf, cur);
        stf(of, O1 + oi, capf, cur);
    }
}

// ---------------------------------------------------------------------------
extern "C" void kernel_launch(void* const* d_in, const int* in_sizes, int n_in,
                              void* d_out, int out_size, void* d_ws, size_t ws_size,
                              hipStream_t stream) {
    const float* xr   = (const float*)d_in[0];
    const float* xi   = (const float*)d_in[1];
    const float* Re   = (const float*)d_in[2];
    const float* w1r  = (const float*)d_in[3];
    const float* w1i  = (const float*)d_in[4];
    const float* b1r  = (const float*)d_in[5];
    const float* b1i  = (const float*)d_in[6];
    const float* w2r  = (const float*)d_in[7];
    const float* w2i  = (const float*)d_in[8];
    const float* b2r  = (const float*)d_in[9];
    const float* b2i  = (const float*)d_in[10];
    const float* w0r  = (const float*)d_in[11];
    const float* w0i  = (const float*)d_in[12];
    const float* wd1r = (const float*)d_in[13];
    const float* wd1i = (const float*)d_in[14];
    const float* wu1r = (const float*)d_in[15];
    const float* wu1i = (const float*)d_in[16];
    const float* wd2r = (const float*)d_in[17];
    const float* wd2i = (const float*)d_in[18];
    const float* wu2r = (const float*)d_in[19];
    const float* wu2i = (const float*)d_in[20];

    float* of  = (float*)d_out;
    i64 capf   = (i64)out_size;   // floats

    k_level0<<<dim3((BB * SP0 + 255) / 256), 256, 0, stream>>>(
        xr, xi, Re, w1r, w1i, b1r, b1i, w2r, w2i, b2r, b2i, w0r, w0i, of, capf);
    k_branch1<<<dim3(8192), 512, 0, stream>>>(
        xr, xi, Re, w1r, w1i, b1r, b1i, w2r, w2i, b2r, b2i, w0r, w0i,
        wd1r, wd1i, wu1r, wu1i, of, capf);
    k_branch2<<<dim3(2048), 512, 0, stream>>>(
        xr, xi, Re, w1r, w1i, b1r, b1i, w2r, w2i, b2r, b2i, w0r, w0i,
        wd1r, wd1i, wu1r, wu1i, wd2r, wd2i, wu2r, wu2i, of, capf);
}

// Round 3
// 529.881 us; speedup vs baseline: 1.9587x; 1.0699x over previous
//
#include <hip/hip_runtime.h>

typedef long long i64;

// ---------------------------------------------------------------------------
// S1=S2=256, B=8, C0=32.  d_out = 22,151,168 float32 = REAL parts of:
//   out0 (8,32,256,129) | out1 (alias of out0) | out2 (8,64,128,64) | out3 (8,64,64,32)
// R9: k_level0 weights via wave-uniform GLOBAL reads (compiler -> s_load,
// SMEM pipe) instead of LDS broadcasts (LDS pipe was the bottleneck:
// ~2300 ds_read_b64 per point-wave vs 47% VALUBusy).  Fused layer2+mask+W0
// c-loop.  gelu division -> v_rcp; sqrt-mask -> squared compare.
// branch1/branch2: wave-per-point (R8 structure), same gelu/mask trims.
// ---------------------------------------------------------------------------
#define BB   8
#define SS1  256
#define MM2  129
#define SP0  (SS1*MM2)    // 33024

#define O0 0LL
#define O1 8454144LL
#define O2 16908288LL
#define O3 21102592LL
// total floats = 22151168

__device__ __forceinline__ float ldf(const float* p, i64 i, i64 cap) {
    return (i >= 0 && i < cap) ? p[i] : 0.0f;
}
__device__ __forceinline__ void stf(float* p, i64 i, i64 cap, float v) {
    if (i >= 0 && i < cap) p[i] = v;
}

__device__ __forceinline__ float tanh_fast(float x) {
    float a = fabsf(x);
    float t = __expf(-2.0f * a);
    // fast reciprocal instead of precise-division sequence (~9 instr saved)
    float r = (1.0f - t) * __builtin_amdgcn_rcpf(1.0f + t);
    return copysignf(r, x);
}
__device__ __forceinline__ float gelu_f(float x) {
    // jax.nn.gelu(approximate=True)
    float inner = 0.7978845608028654f * (x + 0.044715f * x * x * x);
    return 0.5f * x * (1.0f + tanh_fast(inner));
}

// features for point (b, x, y): fr/fi[6] = k-powers, rp[3] = Re-powers
__device__ __forceinline__ void compute_features(
    int b, int x, int y, const float* __restrict__ Re,
    float* fr, float* fi, float* rp)
{
    float kv0 = (x < 128) ? (float)x : (float)(x - 256);
    float kv1 = (y < 128) ? (float)y : -128.0f;
    const float P[3] = {1.0f/3.0f, 2.0f/3.0f, 1.0f};
    #pragma unroll
    for (int d = 0; d < 2; d++) {
        float k = d ? kv1 : kv0;
        float lg = __logf(fabsf(k));
        #pragma unroll
        for (int f = 0; f < 3; f++) {
            int c = f * 2 + d;
            float m = __expf(P[f] * lg);
            if (k == 0.0f)      { fr[c] = 0.0f; fi[c] = 0.0f; }
            else if (k > 0.0f)  { fr[c] = m;    fi[c] = 0.0f; }
            else {
                float ang = P[f] * 3.14159274101257f;
                fr[c] = m * __cosf(ang);
                fi[c] = m * __sinf(ang);
            }
        }
    }
    float lre = __logf(Re[b]);
    #pragma unroll
    for (int f = 0; f < 3; f++) rp[f] = __expf(P[f] * lre);
}

// ---------------------------------------------------------------------------
// K1: thread-per-point; all weight reads wave-uniform -> scalar K$ path.
// Fused layer2 -> mask -> W0 accumulate (no vr/vi arrays).
// ---------------------------------------------------------------------------
__global__ __launch_bounds__(256) void k_level0(
    const float* __restrict__ xr, const float* __restrict__ xi,
    const float* __restrict__ Re,
    const float* __restrict__ w1r, const float* __restrict__ w1i,
    const float* __restrict__ b1r, const float* __restrict__ b1i,
    const float* __restrict__ w2r, const float* __restrict__ w2i,
    const float* __restrict__ b2r, const float* __restrict__ b2i,
    const float* __restrict__ w0r, const float* __restrict__ w0i,
    float* __restrict__ of, i64 capf)
{
    int idx = blockIdx.x * 256 + threadIdx.x;
    if (idx >= BB * SP0) return;
    int y  = idx % MM2;
    int t2 = idx / MM2;
    int x  = t2 % SS1;
    int b  = t2 / SS1;

    float fr[6], fi[6], rp[3];
    compute_features(b, x, y, Re, fr, fi, rp);

    // layer1 (9 -> 32) + cgelu; w1/b1 indices are loop constants (uniform)
    float hr[32], hi[32];
    #pragma unroll
    for (int o = 0; o < 32; o++) {
        float ar = b1r[o], ai = b1i[o];
        #pragma unroll
        for (int i = 0; i < 6; i++) {
            float wr = w1r[o * 9 + i], wi = w1i[o * 9 + i];
            ar += wr * fr[i] - wi * fi[i];
            ai += wr * fi[i] + wi * fr[i];
        }
        #pragma unroll
        for (int f = 0; f < 3; f++) {
            ar += w1r[o * 9 + 6 + f] * rp[f];
            ai += w1i[o * 9 + 6 + f] * rp[f];
        }
        hr[o] = gelu_f(ar);
        hi[o] = gelu_f(ai);
    }

    // fused: per input channel c -> layer2 row -> x*rf -> mask -> W0 accumulate
    float acc[32];
    #pragma unroll
    for (int o = 0; o < 32; o++) acc[o] = 0.0f;

    const float TH2 = 0.05f * 0.05f;
    i64 base0 = (i64)b * 32 * SP0 + (i64)x * MM2 + y;
    for (int c = 0; c < 32; c++) {
        float rr0 = b2r[c], ri0 = b2i[c], rr1 = 0.0f, ri1 = 0.0f;
        #pragma unroll
        for (int i = 0; i < 16; i++) {
            float wr = w2r[c * 32 + i], wi = w2i[c * 32 + i];
            rr0 += wr * hr[i] - wi * hi[i];
            ri0 += wr * hi[i] + wi * hr[i];
        }
        #pragma unroll
        for (int i = 16; i < 32; i++) {
            float wr = w2r[c * 32 + i], wi = w2i[c * 32 + i];
            rr1 += wr * hr[i] - wi * hi[i];
            ri1 += wr * hi[i] + wi * hr[i];
        }
        float rrs = rr0 + rr1, ris = ri0 + ri1;
        float xre = xr[base0 + (i64)c * SP0];
        float xim = xi[base0 + (i64)c * SP0];
        float pr = xre * rrs - xim * ris;
        float pi = xre * ris + xim * rrs;
        if (pr * pr + pi * pi <= TH2) { pr = 0.0f; pi = 0.0f; }
        float vr_c = pr + 1.0f;     // +1 skip: REAL ONLY
        float vi_c = pi;
        #pragma unroll
        for (int o = 0; o < 32; o++) {
            float wr = w0r[c * 32 + o], wi = w0i[c * 32 + o];
            acc[o] += wr * vr_c - wi * vi_c;
        }
    }

    #pragma unroll
    for (int o = 0; o < 32; o++) {
        float g = gelu_f(acc[o]);
        i64 oi = base0 + (i64)o * SP0;
        stf(of, O0 + oi, capf, g);
        stf(of, O1 + oi, capf, g);
    }
}

// ---------------------------------------------------------------------------
// Wave-per-point kernels.  Block = 512 threads = 8 waves = 8 points.
// Per-point LDS scratch (float2): H[32] | V[32] | X1[32] | V1[64] | (V2[64])
// ---------------------------------------------------------------------------
#define PH  0
#define PV  32
#define PX1 64
#define PV1 96
#define PV2 160

// ---------------------------------------------------------------------------
// K2: corner1 \ corner2 points.  idx in [0,65536): y=idx&63, r1=(idx>>6)&127,
// b=idx>>13.  Block covers 8 consecutive y at fixed (b,r1).
// ---------------------------------------------------------------------------
__global__ __launch_bounds__(512, 4) void k_branch1(
    const float* __restrict__ xr, const float* __restrict__ xi,
    const float* __restrict__ Re,
    const float* __restrict__ w1r, const float* __restrict__ w1i,
    const float* __restrict__ b1r, const float* __restrict__ b1i,
    const float* __restrict__ w2r, const float* __restrict__ w2i,
    const float* __restrict__ b2r, const float* __restrict__ b2i,
    const float* __restrict__ w0r, const float* __restrict__ w0i,
    const float* __restrict__ wd1r, const float* __restrict__ wd1i,
    const float* __restrict__ wu1r, const float* __restrict__ wu1i,
    float* __restrict__ of, i64 capf)
{
    int base = blockIdx.x * 8;
    int y0 = base & 63;
    int r1 = (base >> 6) & 127;
    int b  = base >> 13;
    // corner2 points handled by k_branch2 (uniform over block: 8|32)
    if ((y0 < 32) && (r1 < 32 || r1 >= 96)) return;
    int x0 = (r1 < 64) ? r1 : r1 + 128;

    __shared__ float2 s_w2t[1024];           // [i*32+c] (transposed 'oi')
    __shared__ float2 s_w0[1024];            // [i*32+o] natural 'io'
    __shared__ float2 s_wd1[2048];           // [i*64+o] natural 'io'
    __shared__ float2 s_wu1[2048];           // [c*32+o] natural 'io'
    __shared__ float2 s_pt[8][160];
    __shared__ float  s_u[8][32];

    for (int t = threadIdx.x; t < 1024; t += 512) {
        int c = t >> 5, i = t & 31;
        s_w2t[i * 32 + c] = make_float2(w2r[t], w2i[t]);
        s_w0[t] = make_float2(w0r[t], w0i[t]);
    }
    for (int t = threadIdx.x; t < 2048; t += 512) {
        s_wd1[t] = make_float2(wd1r[t], wd1i[t]);
        s_wu1[t] = make_float2(wu1r[t], wu1i[t]);
    }

    int p = threadIdx.x >> 6;         // wave = point
    int lane = threadIdx.x & 63;
    int y = y0 + p;

    // phase A: features + layer1 (9 -> 32), lanes 0..31; w1/b1 from global
    if (lane < 32) {
        float fr[6], fi[6], rp[3];
        compute_features(b, x0, y, Re, fr, fi, rp);
        int o = lane;
        float ar = b1r[o], ai = b1i[o];
        #pragma unroll
        for (int i = 0; i < 6; i++) {
            float wr = w1r[o * 9 + i], wi = w1i[o * 9 + i];
            ar += wr * fr[i] - wi * fi[i];
            ai += wr * fi[i] + wi * fr[i];
        }
        #pragma unroll
        for (int f = 0; f < 3; f++) {
            ar += w1r[o * 9 + 6 + f] * rp[f];
            ai += w1i[o * 9 + 6 + f] * rp[f];
        }
        s_pt[p][PH + o] = make_float2(gelu_f(ar), gelu_f(ai));
    }
    __syncthreads();

    // phase B: layer2 (32 -> 32) + x*rf + mask + skip(+1 real)
    if (lane < 32) {
        int c = lane;
        float rr = b2r[c], ri = b2i[c];
        #pragma unroll
        for (int i = 0; i < 32; i++) {
            float2 w = s_w2t[i * 32 + c];
            float2 h = s_pt[p][PH + i];
            rr += w.x * h.x - w.y * h.y;
            ri += w.x * h.y + w.y * h.x;
        }
        i64 xoff = ((i64)b * 32 + c) * SP0 + (i64)x0 * MM2 + y;
        float xre = xr[xoff], xim = xi[xoff];
        float pr = xre * rr - xim * ri;
        float pi = xre * ri + xim * rr;
        const float TH2 = 0.05f * 0.05f;
        if (pr * pr + pi * pi <= TH2) { pr = 0.0f; pi = 0.0f; }
        s_pt[p][PV + c] = make_float2(pr + 1.0f, pi);
    }
    __syncthreads();

    // phase C: W0 mix -> x1 (complex); lane halves split real/imag parts
    {
        int o = lane & 31, part = lane >> 5;
        const float* vv = (const float*)&s_pt[p][PV];
        int ia = part ? 1 : 0, ib = part ? 0 : 1;
        float sgn = part ? 1.0f : -1.0f;
        float a = 0.0f;
        #pragma unroll
        for (int c2 = 0; c2 < 32; c2++) {
            float2 w = s_w0[c2 * 32 + o];
            a += w.x * vv[2 * c2 + ia] + sgn * w.y * vv[2 * c2 + ib];
        }
        a = gelu_f(a);
        ((float*)&s_pt[p][PX1 + o])[part] = a;
    }
    __syncthreads();

    // phase D: Wd1 (32 -> 64) -> v1 = cgelu + (1 real)
    {
        float ar = 0.0f, ai = 0.0f;
        #pragma unroll
        for (int i2 = 0; i2 < 32; i2++) {
            float2 w = s_wd1[i2 * 64 + lane];
            float2 x1 = s_pt[p][PX1 + i2];
            ar += w.x * x1.x - w.y * x1.y;
            ai += w.x * x1.y + w.y * x1.x;
        }
        s_pt[p][PV1 + lane] = make_float2(gelu_f(ar) + 1.0f, gelu_f(ai));
    }
    __syncthreads();

    // out2 store (y-contiguous): t -> (o, ty)
    {
        int o = threadIdx.x >> 3, ty = threadIdx.x & 7;
        float v = s_pt[ty][PV1 + o].x;
        stf(of, O2 + ((i64)((i64)b * 64 + o) * 128 + r1) * 64 + (y0 + ty), capf, v);
    }

    // phase E: Wu1 real part (64 -> 32); lane halves split c-range, shfl-combine
    {
        int o = lane & 31, half = lane >> 5;
        float acc = 0.0f;
        #pragma unroll
        for (int c2 = 0; c2 < 32; c2++) {
            int c = half * 32 + c2;
            float2 w = s_wu1[c * 32 + o];
            float2 v1 = s_pt[p][PV1 + c];
            acc += w.x * v1.x - w.y * v1.y;
        }
        acc += __shfl_xor(acc, 32);
        if (lane < 32) s_u[p][o] = gelu_f(acc);
    }
    __syncthreads();

    // out0/out1 RMW (y-contiguous)
    if (threadIdx.x < 256) {
        int o = threadIdx.x >> 3, ty = threadIdx.x & 7;
        i64 oi = ((i64)b * 32 + o) * SP0 + (i64)x0 * MM2 + (y0 + ty);
        float cur = ldf(of, O0 + oi, capf) + s_u[ty][o];
        stf(of, O0 + oi, capf, cur);
        stf(of, O1 + oi, capf, cur);
    }
}

// ---------------------------------------------------------------------------
// K3: corner2 points.  idx in [0,16384): y=idx&31, r2=(idx>>5)&63, b=idx>>11.
// wd2/wu2 read straight from global (coalesced 256B/wave, L2-resident) so
// static LDS stays < 64 KB -> 2 blocks/CU.
// ---------------------------------------------------------------------------
__global__ __launch_bounds__(512, 4) void k_branch2(
    const float* __restrict__ xr, const float* __restrict__ xi,
    const float* __restrict__ Re,
    const float* __restrict__ w1r, const float* __restrict__ w1i,
    const float* __restrict__ b1r, const float* __restrict__ b1i,
    const float* __restrict__ w2r, const float* __restrict__ w2i,
    const float* __restrict__ b2r, const float* __restrict__ b2i,
    const float* __restrict__ w0r, const float* __restrict__ w0i,
    const float* __restrict__ wd1r, const float* __restrict__ wd1i,
    const float* __restrict__ wu1r, const float* __restrict__ wu1i,
    const float* __restrict__ wd2r, const float* __restrict__ wd2i,
    const float* __restrict__ wu2r, const float* __restrict__ wu2i,
    float* __restrict__ of, i64 capf)
{
    int base = blockIdx.x * 8;
    int y0 = base & 31;
    int r2 = (base >> 5) & 63;
    int b  = base >> 11;
    int r1 = (r2 < 32) ? r2 : r2 + 64;
    int x0 = (r1 < 64) ? r1 : r1 + 128;

    __shared__ float2 s_w2t[1024];
    __shared__ float2 s_w0[1024];
    __shared__ float2 s_wd1[2048];
    __shared__ float2 s_wu1[2048];
    __shared__ float2 s_pt[8][224];
    __shared__ float  s_u[8][32];

    for (int t = threadIdx.x; t < 1024; t += 512) {
        int c = t >> 5, i = t & 31;
        s_w2t[i * 32 + c] = make_float2(w2r[t], w2i[t]);
        s_w0[t] = make_float2(w0r[t], w0i[t]);
    }
    for (int t = threadIdx.x; t < 2048; t += 512) {
        s_wd1[t] = make_float2(wd1r[t], wd1i[t]);
        s_wu1[t] = make_float2(wu1r[t], wu1i[t]);
    }

    int p = threadIdx.x >> 6;
    int lane = threadIdx.x & 63;
    int y = y0 + p;

    // phase A
    if (lane < 32) {
        float fr[6], fi[6], rp[3];
        compute_features(b, x0, y, Re, fr, fi, rp);
        int o = lane;
        float ar = b1r[o], ai = b1i[o];
        #pragma unroll
        for (int i = 0; i < 6; i++) {
            float wr = w1r[o * 9 + i], wi = w1i[o * 9 + i];
            ar += wr * fr[i] - wi * fi[i];
            ai += wr * fi[i] + wi * fr[i];
        }
        #pragma unroll
        for (int f = 0; f < 3; f++) {
            ar += w1r[o * 9 + 6 + f] * rp[f];
            ai += w1i[o * 9 + 6 + f] * rp[f];
        }
        s_pt[p][PH + o] = make_float2(gelu_f(ar), gelu_f(ai));
    }
    __syncthreads();

    // phase B
    if (lane < 32) {
        int c = lane;
        float rr = b2r[c], ri = b2i[c];
        #pragma unroll
        for (int i = 0; i < 32; i++) {
            float2 w = s_w2t[i * 32 + c];
            float2 h = s_pt[p][PH + i];
            rr += w.x * h.x - w.y * h.y;
            ri += w.x * h.y + w.y * h.x;
        }
        i64 xoff = ((i64)b * 32 + c) * SP0 + (i64)x0 * MM2 + y;
        float xre = xr[xoff], xim = xi[xoff];
        float pr = xre * rr - xim * ri;
        float pi = xre * ri + xim * rr;
        const float TH2 = 0.05f * 0.05f;
        if (pr * pr + pi * pi <= TH2) { pr = 0.0f; pi = 0.0f; }
        s_pt[p][PV + c] = make_float2(pr + 1.0f, pi);
    }
    __syncthreads();

    // phase C
    {
        int o = lane & 31, part = lane >> 5;
        const float* vv = (const float*)&s_pt[p][PV];
        int ia = part ? 1 : 0, ib = part ? 0 : 1;
        float sgn = part ? 1.0f : -1.0f;
        float a = 0.0f;
        #pragma unroll
        for (int c2 = 0; c2 < 32; c2++) {
            float2 w = s_w0[c2 * 32 + o];
            a += w.x * vv[2 * c2 + ia] + sgn * w.y * vv[2 * c2 + ib];
        }
        a = gelu_f(a);
        ((float*)&s_pt[p][PX1 + o])[part] = a;
    }
    __syncthreads();

    // phase D: Wd1 -> v1
    {
        float ar = 0.0f, ai = 0.0f;
        #pragma unroll
        for (int i2 = 0; i2 < 32; i2++) {
            float2 w = s_wd1[i2 * 64 + lane];
            float2 x1 = s_pt[p][PX1 + i2];
            ar += w.x * x1.x - w.y * x1.y;
            ai += w.x * x1.y + w.y * x1.x;
        }
        s_pt[p][PV1 + lane] = make_float2(gelu_f(ar) + 1.0f, gelu_f(ai));
    }
    __syncthreads();

    // phase D2: Wd2 (64 -> 64) -> v2 ; weights from global (coalesced)
    {
        float ar = 0.0f, ai = 0.0f;
        #pragma unroll 8
        for (int c2 = 0; c2 < 64; c2++) {
            float wr = wd2r[c2 * 64 + lane], wi = wd2i[c2 * 64 + lane];
            float2 v1 = s_pt[p][PV1 + c2];
            ar += wr * v1.x - wi * v1.y;
            ai += wr * v1.y + wi * v1.x;
        }
        s_pt[p][PV2 + lane] = make_float2(gelu_f(ar) + 1.0f, gelu_f(ai));
    }
    __syncthreads();

    // out3 store (y-contiguous)
    {
        int o = threadIdx.x >> 3, ty = threadIdx.x & 7;
        float v = s_pt[ty][PV2 + o].x;
        stf(of, O3 + ((i64)((i64)b * 64 + o) * 64 + r2) * 32 + (y0 + ty), capf, v);
    }

    // phase U2: v1 += cgelu(Wu2 mix of v2) ; weights from global (coalesced)
    {
        float ar = 0.0f, ai = 0.0f;
        #pragma unroll 8
        for (int c2 = 0; c2 < 64; c2++) {
            float wr = wu2r[c2 * 64 + lane], wi = wu2i[c2 * 64 + lane];
            float2 v2 = s_pt[p][PV2 + c2];
            ar += wr * v2.x - wi * v2.y;
            ai += wr * v2.y + wi * v2.x;
        }
        float2 v1 = s_pt[p][PV1 + lane];
        v1.x += gelu_f(ar);
        v1.y += gelu_f(ai);
        s_pt[p][PV1 + lane] = v1;
    }
    __syncthreads();

    // out2 store (y-contiguous)
    {
        int o = threadIdx.x >> 3, ty = threadIdx.x & 7;
        float v = s_pt[ty][PV1 + o].x;
        stf(of, O2 + ((i64)((i64)b * 64 + o) * 128 + r1) * 64 + (y0 + ty), capf, v);
    }

    // phase E: Wu1 real part on updated v1
    {
        int o = lane & 31, half = lane >> 5;
        float acc = 0.0f;
        #pragma unroll
        for (int c2 = 0; c2 < 32; c2++) {
            int c = half * 32 + c2;
            float2 w = s_wu1[c * 32 + o];
            float2 v1 = s_pt[p][PV1 + c];
            acc += w.x * v1.x - w.y * v1.y;
        }
        acc += __shfl_xor(acc, 32);
        if (lane < 32) s_u[p][o] = gelu_f(acc);
    }
    __syncthreads();

    if (threadIdx.x < 256) {
        int o = threadIdx.x >> 3, ty = threadIdx.x & 7;
        i64 oi = ((i64)b * 32 + o) * SP0 + (i64)x0 * MM2 + (y0 + ty);
        float cur = ldf(of, O0 + oi, capf) + s_u[ty][o];
        stf(of, O0 + oi, capf, cur);
        stf(of, O1 + oi, capf, cur);
    }
}

// ---------------------------------------------------------------------------
extern "C" void kernel_launch(void* const* d_in, const int* in_sizes, int n_in,
                              void* d_out, int out_size, void* d_ws, size_t ws_size,
                              hipStream_t stream) {
    const float* xr   = (const float*)d_in[0];
    const float* xi   = (const float*)d_in[1];
    const float* Re   = (const float*)d_in[2];
    const float* w1r  = (const float*)d_in[3];
    const float* w1i  = (const float*)d_in[4];
    const float* b1r  = (const float*)d_in[5];
    const float* b1i  = (const float*)d_in[6];
    const float* w2r  = (const float*)d_in[7];
    const float* w2i  = (const float*)d_in[8];
    const float* b2r  = (const float*)d_in[9];
    const float* b2i  = (const float*)d_in[10];
    const float* w0r  = (const float*)d_in[11];
    const float* w0i  = (const float*)d_in[12];
    const float* wd1r = (const float*)d_in[13];
    const float* wd1i = (const float*)d_in[14];
    const float* wu1r = (const float*)d_in[15];
    const float* wu1i = (const float*)d_in[16];
    const float* wd2r = (const float*)d_in[17];
    const float* wd2i = (const float*)d_in[18];
    const float* wu2r = (const float*)d_in[19];
    const float* wu2i = (const float*)d_in[20];

    float* of  = (float*)d_out;
    i64 capf   = (i64)out_size;   // floats

    k_level0<<<dim3((BB * SP0 + 255) / 256), 256, 0, stream>>>(
        xr, xi, Re, w1r, w1i, b1r, b1i, w2r, w2i, b2r, b2i, w0r, w0i, of, capf);
    k_branch1<<<dim3(8192), 512, 0, stream>>>(
        xr, xi, Re, w1r, w1i, b1r, b1i, w2r, w2i, b2r, b2i, w0r, w0i,
        wd1r, wd1i, wu1r, wu1i, of, capf);
    k_branch2<<<dim3(2048), 512, 0, stream>>>(
        xr, xi, Re, w1r, w1i, b1r, b1i, w2r, w2i, b2r, b2i, w0r, w0i,
        wd1r, wd1i, wu1r, wu1i, wd2r, wd2i, wu2r, wu2i, of, capf);
}